// Round 1
// baseline (483.210 us; speedup 1.0000x reference)
//
#include <hip/hip_runtime.h>

#define S_LEN 4096
#define DH    64
#define BQ    128
#define BK    64
#define NTILE (S_LEN / BK)   // 64
#define QBLKS (S_LEN / BQ)   // 32
#define NBH   24             // B*H = 2*12

typedef __attribute__((ext_vector_type(8))) short short8;   // 8 bf16 (4 VGPRs) MFMA frag
typedef __attribute__((ext_vector_type(4))) short short4v;  // 4 bf16 (b64 LDS store)
typedef __attribute__((ext_vector_type(4))) float f32x4;    // MFMA accum

// LDS strides (elements). *2 bytes must be mult of 16 for ds_read_b128 alignment.
#define KSTR 72   // 64 + 8 pad
#define VSTR 72
#define PSTR 72

#define LOG2E 1.44269504088896f

__device__ __forceinline__ short f2bf(float x) {
    unsigned u = __builtin_bit_cast(unsigned, x);
    return (short)((u + 0x8000u) >> 16);   // round-to-nearest (ties up)
}

__global__ __launch_bounds__(256, 4)
void fa_kernel(const float* __restrict__ Q, const float* __restrict__ K,
               const float* __restrict__ V, const float* __restrict__ M,
               float* __restrict__ O)
{
    __shared__ __align__(16) short K_lds[BK * KSTR];    // [key][d]      9216 B
    __shared__ __align__(16) short Vt_lds[DH * VSTR];   // [d][key]      9216 B
    __shared__ __align__(16) short P_lds[BQ * PSTR];    // [q][key]     18432 B
    __shared__ __align__(16) float mask_lds[BK];        //                256 B

    const int tid  = threadIdx.x;
    const int w    = tid >> 6;      // wave 0..3
    const int lane = tid & 63;
    const int n    = lane & 15;
    const int quad = lane >> 4;

    // XCD-aware swizzle: all 32 q-blocks of one (b,h) share bid&7 (same XCD
    // under round-robin dispatch) so K/V of that head stays in one L2.
    const int bid  = blockIdx.x;
    const int x    = bid & 7;
    const int g    = bid >> 3;            // 0..95
    const int bh   = x + 8 * (g >> 5);    // 0..23
    const int qblk = g & 31;
    const bool special = (qblk == QBLKS - 1);

    const size_t base  = (size_t)bh * S_LEN * DH;
    const int    b_idx = bh / 12;         // H = 12

    // ---- Q fragments in registers, scaled by 0.125*log2(e) (log2-domain scores)
    const float QSCALE = 0.125f * LOG2E;
    const int q0 = qblk * BQ + w * 32;
    short8 qf[2][2];   // [nsub][kstep]  B-frag: B[k=d][n=q], q = q0+16s+n, d = 32kt+8quad+j
    #pragma unroll
    for (int s = 0; s < 2; ++s) {
        const float* qp = Q + base + (size_t)(q0 + 16 * s + n) * DH;
        #pragma unroll
        for (int kt = 0; kt < 2; ++kt) {
            const float* p = qp + 32 * kt + 8 * quad;
            float4 a = *(const float4*)p;
            float4 b = *(const float4*)(p + 4);
            short8 f;
            f[0] = f2bf(a.x * QSCALE); f[1] = f2bf(a.y * QSCALE);
            f[2] = f2bf(a.z * QSCALE); f[3] = f2bf(a.w * QSCALE);
            f[4] = f2bf(b.x * QSCALE); f[5] = f2bf(b.y * QSCALE);
            f[6] = f2bf(b.z * QSCALE); f[7] = f2bf(b.w * QSCALE);
            qf[s][kt] = f;
        }
    }

    // O^T accumulators: C row = d = 16*dsub + 4*quad + r, col = q = 16*s + n
    f32x4 o[4][2];
    #pragma unroll
    for (int d = 0; d < 4; ++d)
        #pragma unroll
        for (int s = 0; s < 2; ++s) o[d][s] = (f32x4){0.f, 0.f, 0.f, 0.f};
    float m_r[2] = {-INFINITY, -INFINITY};
    float l_r[2] = {0.f, 0.f};

    for (int t = 0; t < NTILE; ++t) {
        const int key0 = t * BK;

        // ---- stage K tile: [64 keys][64 d] fp32 -> bf16 LDS (coalesced float4)
        #pragma unroll
        for (int it = 0; it < 4; ++it) {
            int idx = tid + 256 * it;         // 0..1023
            int row = idx >> 4, c4 = idx & 15;
            float4 v = *(const float4*)(K + base + (size_t)(key0 + row) * DH + 4 * c4);
            short4v b4 = { f2bf(v.x), f2bf(v.y), f2bf(v.z), f2bf(v.w) };
            *(short4v*)&K_lds[row * KSTR + 4 * c4] = b4;
        }
        // ---- stage V transposed: thread owns a 4x4 block, writes 4x ds_write_b64
        {
            int kb = tid >> 4, db = tid & 15; // kb:0..15 (4 keys), db:0..15 (4 d)
            const float* vp = V + base + (size_t)(key0 + 4 * kb) * DH + 4 * db;
            float4 r0 = *(const float4*)(vp);
            float4 r1 = *(const float4*)(vp + DH);
            float4 r2 = *(const float4*)(vp + 2 * DH);
            float4 r3 = *(const float4*)(vp + 3 * DH);
            short4v c0 = { f2bf(r0.x), f2bf(r1.x), f2bf(r2.x), f2bf(r3.x) };
            short4v c1 = { f2bf(r0.y), f2bf(r1.y), f2bf(r2.y), f2bf(r3.y) };
            short4v c2 = { f2bf(r0.z), f2bf(r1.z), f2bf(r2.z), f2bf(r3.z) };
            short4v c3 = { f2bf(r0.w), f2bf(r1.w), f2bf(r2.w), f2bf(r3.w) };
            *(short4v*)&Vt_lds[(4 * db + 0) * VSTR + 4 * kb] = c0;
            *(short4v*)&Vt_lds[(4 * db + 1) * VSTR + 4 * kb] = c1;
            *(short4v*)&Vt_lds[(4 * db + 2) * VSTR + 4 * kb] = c2;
            *(short4v*)&Vt_lds[(4 * db + 3) * VSTR + 4 * kb] = c3;
        }
        // ---- stage mask (pre-scaled to log2 domain)
        if (tid < 16) {
            float4 mv = *(const float4*)(M + (size_t)b_idx * S_LEN + key0 + 4 * tid);
            mv.x *= LOG2E; mv.y *= LOG2E; mv.z *= LOG2E; mv.w *= LOG2E;
            *(float4*)&mask_lds[4 * tid] = mv;
        }
        __syncthreads();

        // ---- S^T = K*Q^T :  A = K-frag (m=key), B = Q-frag (n=q)
        // C layout: row = key = 16*mt + 4*quad + r, col = q = 16*s + n
        f32x4 acc[4][2];
        if (special && t >= NTILE - 2) {
            // reference OVERWRITES last 128x128 scores: 0 on/below diag, -inf above
            #pragma unroll
            for (int mt = 0; mt < 4; ++mt)
                #pragma unroll
                for (int s = 0; s < 2; ++s) {
                    int ql = w * 32 + 16 * s + n;                       // 0..127
                    #pragma unroll
                    for (int r = 0; r < 4; ++r) {
                        int kl = (t - (NTILE - 2)) * BK + 16 * mt + 4 * quad + r;
                        acc[mt][s][r] = (kl > ql) ? -INFINITY : 0.0f;
                    }
                }
        } else {
            #pragma unroll
            for (int mt = 0; mt < 4; ++mt) {
                short8 k0f = *(const short8*)&K_lds[(16 * mt + n) * KSTR + 8 * quad];
                short8 k1f = *(const short8*)&K_lds[(16 * mt + n) * KSTR + 32 + 8 * quad];
                #pragma unroll
                for (int s = 0; s < 2; ++s) {
                    f32x4 c = (f32x4){0.f, 0.f, 0.f, 0.f};
                    c = __builtin_amdgcn_mfma_f32_16x16x32_bf16(k0f, qf[s][0], c, 0, 0, 0);
                    c = __builtin_amdgcn_mfma_f32_16x16x32_bf16(k1f, qf[s][1], c, 0, 0, 0);
                    acc[mt][s] = c;
                }
                f32x4 mk = *(const f32x4*)&mask_lds[16 * mt + 4 * quad];
                acc[mt][0] += mk;
                acc[mt][1] += mk;
            }
        }

        // ---- online softmax (log2 domain), per nsub; stats are per-lane (q = n+16s)
        #pragma unroll
        for (int s = 0; s < 2; ++s) {
            float mx = -INFINITY;
            #pragma unroll
            for (int mt = 0; mt < 4; ++mt)
                #pragma unroll
                for (int r = 0; r < 4; ++r) mx = fmaxf(mx, acc[mt][s][r]);
            mx = fmaxf(mx, __shfl_xor(mx, 16));
            mx = fmaxf(mx, __shfl_xor(mx, 32));
            float mn = fmaxf(m_r[s], mx);
            float alpha = exp2f(m_r[s] - mn);
            m_r[s] = mn;
            float sum = 0.f;
            #pragma unroll
            for (int mt = 0; mt < 4; ++mt)
                #pragma unroll
                for (int r = 0; r < 4; ++r) {
                    float p = exp2f(acc[mt][s][r] - mn);
                    acc[mt][s][r] = p;
                    sum += p;
                }
            sum += __shfl_xor(sum, 16);
            sum += __shfl_xor(sum, 32);
            l_r[s] = l_r[s] * alpha + sum;
            #pragma unroll
            for (int d = 0; d < 4; ++d) o[d][s] *= alpha;

            // ---- P^T -> LDS: 4 consecutive keys per C-frag pack into one b64
            int qrow = w * 32 + 16 * s + n;
            #pragma unroll
            for (int mt = 0; mt < 4; ++mt) {
                short4v pb = { f2bf(acc[mt][s][0]), f2bf(acc[mt][s][1]),
                               f2bf(acc[mt][s][2]), f2bf(acc[mt][s][3]) };
                *(short4v*)&P_lds[qrow * PSTR + 16 * mt + 4 * quad] = pb;
            }
        }

        // ---- O^T += V^T * P^T :  A = Vt-frag (m=d), B = P-frag (n=q)
        #pragma unroll
        for (int kt2 = 0; kt2 < 2; ++kt2) {
            short8 pf0 = *(const short8*)&P_lds[(w * 32 + n) * PSTR + 32 * kt2 + 8 * quad];
            short8 pf1 = *(const short8*)&P_lds[(w * 32 + 16 + n) * PSTR + 32 * kt2 + 8 * quad];
            #pragma unroll
            for (int d = 0; d < 4; ++d) {
                short8 vf = *(const short8*)&Vt_lds[(16 * d + n) * VSTR + 32 * kt2 + 8 * quad];
                o[d][0] = __builtin_amdgcn_mfma_f32_16x16x32_bf16(vf, pf0, o[d][0], 0, 0, 0);
                o[d][1] = __builtin_amdgcn_mfma_f32_16x16x32_bf16(vf, pf1, o[d][1], 0, 0, 0);
            }
        }
        __syncthreads();
    }

    // ---- epilogue: out[q][d] = O^T[d][q] / l(q)  — float4 stores (r = consecutive d)
    #pragma unroll
    for (int s = 0; s < 2; ++s) {
        float inv = 1.0f / l_r[s];
        int qg = q0 + 16 * s + n;
        float* op = O + base + (size_t)qg * DH;
        #pragma unroll
        for (int d = 0; d < 4; ++d) {
            f32x4 r = o[d][s] * inv;
            *(f32x4*)(op + 16 * d + 4 * quad) = r;
        }
    }
}

extern "C" void kernel_launch(void* const* d_in, const int* in_sizes, int n_in,
                              void* d_out, int out_size, void* d_ws, size_t ws_size,
                              hipStream_t stream) {
    const float* Q = (const float*)d_in[0];
    const float* K = (const float*)d_in[1];
    const float* V = (const float*)d_in[2];
    const float* M = (const float*)d_in[3];
    float* O = (float*)d_out;
    fa_kernel<<<dim3(NBH * QBLKS), dim3(256), 0, stream>>>(Q, K, V, M, O);
}

// Round 2
// 270.207 us; speedup vs baseline: 1.7883x; 1.7883x over previous
//
#include <hip/hip_runtime.h>

#define S_LEN 4096
#define DH    64
#define BQ    128
#define BK    64
#define NTILE (S_LEN / BK)   // 64
#define QBLKS (S_LEN / BQ)   // 32
#define NBH   24             // B*H = 2*12
#define NHEADS 12

typedef __attribute__((ext_vector_type(8))) short short8;   // 8 bf16 (4 VGPRs) MFMA frag
typedef __attribute__((ext_vector_type(4))) short short4v;  // 4 bf16 (b64 LDS store)
typedef __attribute__((ext_vector_type(4))) float f32x4;    // MFMA accum

#define PSTR 72   // P LDS stride (shorts); *2B multiple of 16 for ds_read_b128
#define LOG2E 1.44269504088896f

// 16B chunks per tensor in fragment layout: 24*4096*64 elems / 8 per chunk
#define NK (NBH * S_LEN * DH / 8)      // 786432
#define MASK_CHUNKS (2 * S_LEN / 4)    // 2048
#define WS_NEEDED ((size_t)NK * 16 * 2 + 2 * S_LEN * 4)

__device__ __forceinline__ short f2bf(float x) {
    unsigned u = __builtin_bit_cast(unsigned, x);
    return (short)((u + 0x8000u) >> 16);   // round-to-nearest (ties up)
}

// ============================================================================
// Prepass: K -> bf16 A-frag order, V -> bf16 V^T A-frag order, mask -> *log2e
// Kf chunk c = (((bh*64+t)*4+mt)*2+kt)*64 + lane ; elem j = K[key=64t+16mt+n][d=32kt+8q+j]
// Vtf chunk c = (((bh*64+t)*2+kt2)*4+d)*64 + lane ; elem j = V[64t+32kt2+8q+j][16d+n]
// ============================================================================
__global__ __launch_bounds__(256)
void prepass(const float* __restrict__ K, const float* __restrict__ V,
             const float* __restrict__ M, short* __restrict__ Kf,
             short* __restrict__ Vtf, float* __restrict__ Mf)
{
    int id = blockIdx.x * 256 + threadIdx.x;
    if (id < NK) {
        int c = id;
        int lane = c & 63, kt = (c >> 6) & 1, mt = (c >> 7) & 3, t = (c >> 9) & 63, bh = c >> 15;
        int n = lane & 15, q = lane >> 4;
        const float* src = K + ((size_t)bh * S_LEN + 64 * t + 16 * mt + n) * DH + 32 * kt + 8 * q;
        float4 a = *(const float4*)src;
        float4 b = *(const float4*)(src + 4);
        short8 f = { f2bf(a.x), f2bf(a.y), f2bf(a.z), f2bf(a.w),
                     f2bf(b.x), f2bf(b.y), f2bf(b.z), f2bf(b.w) };
        *(short8*)&Kf[(size_t)c * 8] = f;
    } else if (id < 2 * NK) {
        int c = id - NK;
        int lane = c & 63, d = (c >> 6) & 3, kt2 = (c >> 8) & 1, t = (c >> 9) & 63, bh = c >> 15;
        int n = lane & 15, q = lane >> 4;
        const float* src = V + ((size_t)bh * S_LEN + 64 * t + 32 * kt2 + 8 * q) * DH + 16 * d + n;
        short8 f;
        #pragma unroll
        for (int j = 0; j < 8; ++j) f[j] = f2bf(src[(size_t)j * DH]);
        *(short8*)&Vtf[(size_t)c * 8] = f;
    } else if (id < 2 * NK + MASK_CHUNKS) {
        int c = id - 2 * NK;
        float4 mv = ((const float4*)M)[c];
        mv.x *= LOG2E; mv.y *= LOG2E; mv.z *= LOG2E; mv.w *= LOG2E;
        ((float4*)Mf)[c] = mv;
    }
}

// ============================================================================
// Flash kernel v2: barrier-free; K/V fragments direct from global (pre-swizzled)
// ============================================================================
__global__ __launch_bounds__(256, 3)
void fa2(const float* __restrict__ Q, const short* __restrict__ Kf,
         const short* __restrict__ Vtf, const float* __restrict__ Mf,
         float* __restrict__ O)
{
    __shared__ __align__(16) short P_lds[BQ * PSTR];   // wave-local P round-trip only

    const int tid  = threadIdx.x;
    const int w    = tid >> 6;
    const int lane = tid & 63;
    const int n    = lane & 15;
    const int quad = lane >> 4;

    const int bid  = blockIdx.x;
    const int x    = bid & 7;
    const int g    = bid >> 3;
    const int bh   = x + 8 * (g >> 5);
    const int qblk = g & 31;
    const bool special = (qblk == QBLKS - 1);

    const size_t base  = (size_t)bh * S_LEN * DH;
    const int    b_idx = bh / NHEADS;

    // ---- Q fragments (fp32 -> bf16, scaled by 0.125*log2e), once per block
    const float QSCALE = 0.125f * LOG2E;
    const int q0 = qblk * BQ + w * 32;
    short8 qf[2][2];
    #pragma unroll
    for (int s = 0; s < 2; ++s) {
        const float* qp = Q + base + (size_t)(q0 + 16 * s + n) * DH;
        #pragma unroll
        for (int kt = 0; kt < 2; ++kt) {
            const float* p = qp + 32 * kt + 8 * quad;
            float4 a = *(const float4*)p;
            float4 b = *(const float4*)(p + 4);
            short8 f;
            f[0] = f2bf(a.x * QSCALE); f[1] = f2bf(a.y * QSCALE);
            f[2] = f2bf(a.z * QSCALE); f[3] = f2bf(a.w * QSCALE);
            f[4] = f2bf(b.x * QSCALE); f[5] = f2bf(b.y * QSCALE);
            f[6] = f2bf(b.z * QSCALE); f[7] = f2bf(b.w * QSCALE);
            qf[s][kt] = f;
        }
    }

    f32x4 o[4][2];
    #pragma unroll
    for (int d = 0; d < 4; ++d)
        #pragma unroll
        for (int s = 0; s < 2; ++s) o[d][s] = (f32x4){0.f, 0.f, 0.f, 0.f};
    float m_r[2] = {-INFINITY, -INFINITY};
    float l_r[2] = {0.f, 0.f};

    const float* mrow = Mf + (size_t)b_idx * S_LEN;

    for (int t = 0; t < NTILE; ++t) {
        f32x4 acc[4][2];

        if (special && t >= NTILE - 2) {
            // reference OVERWRITES last 128x128 scores: 0 on/below diag, -inf above
            #pragma unroll
            for (int mt = 0; mt < 4; ++mt)
                #pragma unroll
                for (int s = 0; s < 2; ++s) {
                    int ql = w * 32 + 16 * s + n;
                    #pragma unroll
                    for (int r = 0; r < 4; ++r) {
                        int kl = (t - (NTILE - 2)) * BK + 16 * mt + 4 * quad + r;
                        acc[mt][s][r] = (kl > ql) ? -INFINITY : 0.0f;
                    }
                }
        } else {
            // ---- K fragments straight from global (A-frag order)
            const short* kb = Kf + (size_t)(bh * 64 + t) * 4096 + (size_t)lane * 8;
            short8 kfr[4][2];
            #pragma unroll
            for (int mt = 0; mt < 4; ++mt)
                #pragma unroll
                for (int kt = 0; kt < 2; ++kt)
                    kfr[mt][kt] = *(const short8*)(kb + (mt * 2 + kt) * 512);

            #pragma unroll
            for (int mt = 0; mt < 4; ++mt) {
                #pragma unroll
                for (int s = 0; s < 2; ++s) {
                    f32x4 c = (f32x4){0.f, 0.f, 0.f, 0.f};
                    c = __builtin_amdgcn_mfma_f32_16x16x32_bf16(kfr[mt][0], qf[s][0], c, 0, 0, 0);
                    c = __builtin_amdgcn_mfma_f32_16x16x32_bf16(kfr[mt][1], qf[s][1], c, 0, 0, 0);
                    acc[mt][s] = c;
                }
                f32x4 mk = *(const f32x4*)(mrow + t * 64 + 16 * mt + 4 * quad);
                acc[mt][0] += mk;
                acc[mt][1] += mk;
            }
        }

        // ---- online softmax (log2 domain); stats per-lane (q = n + 16s)
        #pragma unroll
        for (int s = 0; s < 2; ++s) {
            float mx = -INFINITY;
            #pragma unroll
            for (int mt = 0; mt < 4; ++mt)
                #pragma unroll
                for (int r = 0; r < 4; ++r) mx = fmaxf(mx, acc[mt][s][r]);
            mx = fmaxf(mx, __shfl_xor(mx, 16));
            mx = fmaxf(mx, __shfl_xor(mx, 32));
            float mn = fmaxf(m_r[s], mx);
            float alpha = __builtin_amdgcn_exp2f(m_r[s] - mn);
            m_r[s] = mn;
            float sum = 0.f;
            #pragma unroll
            for (int mt = 0; mt < 4; ++mt)
                #pragma unroll
                for (int r = 0; r < 4; ++r) {
                    float p = __builtin_amdgcn_exp2f(acc[mt][s][r] - mn);
                    acc[mt][s][r] = p;
                    sum += p;
                }
            sum += __shfl_xor(sum, 16);
            sum += __shfl_xor(sum, 32);
            l_r[s] = l_r[s] * alpha + sum;
            #pragma unroll
            for (int d = 0; d < 4; ++d) o[d][s] *= alpha;

            // P^T C-frag -> LDS (wave-local rows; no barrier needed)
            int qrow = w * 32 + 16 * s + n;
            #pragma unroll
            for (int mt = 0; mt < 4; ++mt) {
                short4v pb = { f2bf(acc[mt][s][0]), f2bf(acc[mt][s][1]),
                               f2bf(acc[mt][s][2]), f2bf(acc[mt][s][3]) };
                *(short4v*)&P_lds[qrow * PSTR + 16 * mt + 4 * quad] = pb;
            }
        }

        // ---- V^T fragments straight from global (A-frag order)
        const short* vb = Vtf + (size_t)(bh * 64 + t) * 4096 + (size_t)lane * 8;
        short8 vfr[2][4];
        #pragma unroll
        for (int kt2 = 0; kt2 < 2; ++kt2)
            #pragma unroll
            for (int d = 0; d < 4; ++d)
                vfr[kt2][d] = *(const short8*)(vb + (kt2 * 4 + d) * 512);

        // ---- O^T += V^T * P^T
        #pragma unroll
        for (int kt2 = 0; kt2 < 2; ++kt2) {
            short8 pf0 = *(const short8*)&P_lds[(w * 32 + n) * PSTR + 32 * kt2 + 8 * quad];
            short8 pf1 = *(const short8*)&P_lds[(w * 32 + 16 + n) * PSTR + 32 * kt2 + 8 * quad];
            #pragma unroll
            for (int d = 0; d < 4; ++d) {
                o[d][0] = __builtin_amdgcn_mfma_f32_16x16x32_bf16(vfr[kt2][d], pf0, o[d][0], 0, 0, 0);
                o[d][1] = __builtin_amdgcn_mfma_f32_16x16x32_bf16(vfr[kt2][d], pf1, o[d][1], 0, 0, 0);
            }
        }
    }

    // ---- epilogue
    #pragma unroll
    for (int s = 0; s < 2; ++s) {
        float inv = 1.0f / l_r[s];
        int qg = q0 + 16 * s + n;
        float* op = O + base + (size_t)qg * DH;
        #pragma unroll
        for (int d = 0; d < 4; ++d) {
            f32x4 r = o[d][s] * inv;
            *(f32x4*)(op + 16 * d + 4 * quad) = r;
        }
    }
}

// ============================================================================
// Fallback (round-1 kernel, used only if ws_size is too small) — known-correct
// ============================================================================
#define KSTR 72
#define VSTR 72

__global__ __launch_bounds__(256, 4)
void fa_kernel(const float* __restrict__ Q, const float* __restrict__ K,
               const float* __restrict__ V, const float* __restrict__ M,
               float* __restrict__ O)
{
    __shared__ __align__(16) short K_lds[BK * KSTR];
    __shared__ __align__(16) short Vt_lds[DH * VSTR];
    __shared__ __align__(16) short P_lds[BQ * PSTR];
    __shared__ __align__(16) float mask_lds[BK];

    const int tid  = threadIdx.x;
    const int w    = tid >> 6;
    const int lane = tid & 63;
    const int n    = lane & 15;
    const int quad = lane >> 4;

    const int bid  = blockIdx.x;
    const int x    = bid & 7;
    const int g    = bid >> 3;
    const int bh   = x + 8 * (g >> 5);
    const int qblk = g & 31;
    const bool special = (qblk == QBLKS - 1);

    const size_t base  = (size_t)bh * S_LEN * DH;
    const int    b_idx = bh / NHEADS;

    const float QSCALE = 0.125f * LOG2E;
    const int q0 = qblk * BQ + w * 32;
    short8 qf[2][2];
    #pragma unroll
    for (int s = 0; s < 2; ++s) {
        const float* qp = Q + base + (size_t)(q0 + 16 * s + n) * DH;
        #pragma unroll
        for (int kt = 0; kt < 2; ++kt) {
            const float* p = qp + 32 * kt + 8 * quad;
            float4 a = *(const float4*)p;
            float4 b = *(const float4*)(p + 4);
            short8 f;
            f[0] = f2bf(a.x * QSCALE); f[1] = f2bf(a.y * QSCALE);
            f[2] = f2bf(a.z * QSCALE); f[3] = f2bf(a.w * QSCALE);
            f[4] = f2bf(b.x * QSCALE); f[5] = f2bf(b.y * QSCALE);
            f[6] = f2bf(b.z * QSCALE); f[7] = f2bf(b.w * QSCALE);
            qf[s][kt] = f;
        }
    }

    f32x4 o[4][2];
    #pragma unroll
    for (int d = 0; d < 4; ++d)
        #pragma unroll
        for (int s = 0; s < 2; ++s) o[d][s] = (f32x4){0.f, 0.f, 0.f, 0.f};
    float m_r[2] = {-INFINITY, -INFINITY};
    float l_r[2] = {0.f, 0.f};

    for (int t = 0; t < NTILE; ++t) {
        const int key0 = t * BK;
        #pragma unroll
        for (int it = 0; it < 4; ++it) {
            int idx = tid + 256 * it;
            int row = idx >> 4, c4 = idx & 15;
            float4 v = *(const float4*)(K + base + (size_t)(key0 + row) * DH + 4 * c4);
            short4v b4 = { f2bf(v.x), f2bf(v.y), f2bf(v.z), f2bf(v.w) };
            *(short4v*)&K_lds[row * KSTR + 4 * c4] = b4;
        }
        {
            int kb = tid >> 4, db = tid & 15;
            const float* vp = V + base + (size_t)(key0 + 4 * kb) * DH + 4 * db;
            float4 r0 = *(const float4*)(vp);
            float4 r1 = *(const float4*)(vp + DH);
            float4 r2 = *(const float4*)(vp + 2 * DH);
            float4 r3 = *(const float4*)(vp + 3 * DH);
            short4v c0 = { f2bf(r0.x), f2bf(r1.x), f2bf(r2.x), f2bf(r3.x) };
            short4v c1 = { f2bf(r0.y), f2bf(r1.y), f2bf(r2.y), f2bf(r3.y) };
            short4v c2 = { f2bf(r0.z), f2bf(r1.z), f2bf(r2.z), f2bf(r3.z) };
            short4v c3 = { f2bf(r0.w), f2bf(r1.w), f2bf(r2.w), f2bf(r3.w) };
            *(short4v*)&Vt_lds[(4 * db + 0) * VSTR + 4 * kb] = c0;
            *(short4v*)&Vt_lds[(4 * db + 1) * VSTR + 4 * kb] = c1;
            *(short4v*)&Vt_lds[(4 * db + 2) * VSTR + 4 * kb] = c2;
            *(short4v*)&Vt_lds[(4 * db + 3) * VSTR + 4 * kb] = c3;
        }
        if (tid < 16) {
            float4 mv = *(const float4*)(M + (size_t)b_idx * S_LEN + key0 + 4 * tid);
            mv.x *= LOG2E; mv.y *= LOG2E; mv.z *= LOG2E; mv.w *= LOG2E;
            *(float4*)&mask_lds[4 * tid] = mv;
        }
        __syncthreads();

        f32x4 acc[4][2];
        if (special && t >= NTILE - 2) {
            #pragma unroll
            for (int mt = 0; mt < 4; ++mt)
                #pragma unroll
                for (int s = 0; s < 2; ++s) {
                    int ql = w * 32 + 16 * s + n;
                    #pragma unroll
                    for (int r = 0; r < 4; ++r) {
                        int kl = (t - (NTILE - 2)) * BK + 16 * mt + 4 * quad + r;
                        acc[mt][s][r] = (kl > ql) ? -INFINITY : 0.0f;
                    }
                }
        } else {
            #pragma unroll
            for (int mt = 0; mt < 4; ++mt) {
                short8 k0f = *(const short8*)&K_lds[(16 * mt + n) * KSTR + 8 * quad];
                short8 k1f = *(const short8*)&K_lds[(16 * mt + n) * KSTR + 32 + 8 * quad];
                #pragma unroll
                for (int s = 0; s < 2; ++s) {
                    f32x4 c = (f32x4){0.f, 0.f, 0.f, 0.f};
                    c = __builtin_amdgcn_mfma_f32_16x16x32_bf16(k0f, qf[s][0], c, 0, 0, 0);
                    c = __builtin_amdgcn_mfma_f32_16x16x32_bf16(k1f, qf[s][1], c, 0, 0, 0);
                    acc[mt][s] = c;
                }
                f32x4 mk = *(const f32x4*)&mask_lds[16 * mt + 4 * quad];
                acc[mt][0] += mk;
                acc[mt][1] += mk;
            }
        }

        #pragma unroll
        for (int s = 0; s < 2; ++s) {
            float mx = -INFINITY;
            #pragma unroll
            for (int mt = 0; mt < 4; ++mt)
                #pragma unroll
                for (int r = 0; r < 4; ++r) mx = fmaxf(mx, acc[mt][s][r]);
            mx = fmaxf(mx, __shfl_xor(mx, 16));
            mx = fmaxf(mx, __shfl_xor(mx, 32));
            float mn = fmaxf(m_r[s], mx);
            float alpha = __builtin_amdgcn_exp2f(m_r[s] - mn);
            m_r[s] = mn;
            float sum = 0.f;
            #pragma unroll
            for (int mt = 0; mt < 4; ++mt)
                #pragma unroll
                for (int r = 0; r < 4; ++r) {
                    float p = __builtin_amdgcn_exp2f(acc[mt][s][r] - mn);
                    acc[mt][s][r] = p;
                    sum += p;
                }
            sum += __shfl_xor(sum, 16);
            sum += __shfl_xor(sum, 32);
            l_r[s] = l_r[s] * alpha + sum;
            #pragma unroll
            for (int d = 0; d < 4; ++d) o[d][s] *= alpha;

            int qrow = w * 32 + 16 * s + n;
            #pragma unroll
            for (int mt = 0; mt < 4; ++mt) {
                short4v pb = { f2bf(acc[mt][s][0]), f2bf(acc[mt][s][1]),
                               f2bf(acc[mt][s][2]), f2bf(acc[mt][s][3]) };
                *(short4v*)&P_lds[qrow * PSTR + 16 * mt + 4 * quad] = pb;
            }
        }

        #pragma unroll
        for (int kt2 = 0; kt2 < 2; ++kt2) {
            short8 pf0 = *(const short8*)&P_lds[(w * 32 + n) * PSTR + 32 * kt2 + 8 * quad];
            short8 pf1 = *(const short8*)&P_lds[(w * 32 + 16 + n) * PSTR + 32 * kt2 + 8 * quad];
            #pragma unroll
            for (int d = 0; d < 4; ++d) {
                short8 vf = *(const short8*)&Vt_lds[(16 * d + n) * VSTR + 32 * kt2 + 8 * quad];
                o[d][0] = __builtin_amdgcn_mfma_f32_16x16x32_bf16(vf, pf0, o[d][0], 0, 0, 0);
                o[d][1] = __builtin_amdgcn_mfma_f32_16x16x32_bf16(vf, pf1, o[d][1], 0, 0, 0);
            }
        }
        __syncthreads();
    }

    #pragma unroll
    for (int s = 0; s < 2; ++s) {
        float inv = 1.0f / l_r[s];
        int qg = q0 + 16 * s + n;
        float* op = O + base + (size_t)qg * DH;
        #pragma unroll
        for (int d = 0; d < 4; ++d) {
            f32x4 r = o[d][s] * inv;
            *(f32x4*)(op + 16 * d + 4 * quad) = r;
        }
    }
}

extern "C" void kernel_launch(void* const* d_in, const int* in_sizes, int n_in,
                              void* d_out, int out_size, void* d_ws, size_t ws_size,
                              hipStream_t stream) {
    const float* Q = (const float*)d_in[0];
    const float* K = (const float*)d_in[1];
    const float* V = (const float*)d_in[2];
    const float* M = (const float*)d_in[3];
    float* O = (float*)d_out;

    if (ws_size >= WS_NEEDED) {
        short* Kf  = (short*)d_ws;
        short* Vtf = Kf + (size_t)NK * 8;
        float* Mf  = (float*)(Vtf + (size_t)NK * 8);
        int total = 2 * NK + MASK_CHUNKS;
        prepass<<<dim3((total + 255) / 256), dim3(256), 0, stream>>>(K, V, M, Kf, Vtf, Mf);
        fa2<<<dim3(NBH * QBLKS), dim3(256), 0, stream>>>(Q, Kf, Vtf, Mf, O);
    } else {
        fa_kernel<<<dim3(NBH * QBLKS), dim3(256), 0, stream>>>(Q, K, V, M, O);
    }
}

// Round 3
// 255.244 us; speedup vs baseline: 1.8931x; 1.0586x over previous
//
#include <hip/hip_runtime.h>

#define S_LEN 4096
#define DH    64
#define BQ    128
#define BK    64
#define NTILE (S_LEN / BK)   // 64
#define QBLKS (S_LEN / BQ)   // 32
#define NBH   24             // B*H
#define NHEADS 12

typedef __attribute__((ext_vector_type(8))) short short8;   // 8 bf16 MFMA frag
typedef __attribute__((ext_vector_type(4))) short short4v;  // 4 bf16 (b64)
typedef __attribute__((ext_vector_type(4))) float f32x4;    // MFMA accum

#define PSTR 72
#define KSTR 72
#define VSTR 72
#define LOG2E 1.44269504088896f
// fixed softmax shift (2^-13) + truncation-rounding compensation log2(1+2^-9):
// p = exp2(score*log2e + mask*log2e - 13 + 0.0028157)  -- softmax-invariant shift
#define MCONST (-12.99718425f)

// 16B chunks per tensor in fragment layout
#define NKCH (NBH * S_LEN * DH / 8)    // 786432
#define WS_NEEDED ((size_t)NKCH * 16 * 2 + 2 * (size_t)S_LEN * 4)

__device__ __forceinline__ short f2bf(float x) {
    unsigned u = __builtin_bit_cast(unsigned, x);
    return (short)((u + 0x8000u) >> 16);   // round-to-nearest
}

// ============================================================================
// Prepass v2: one block per (bh, key-tile). Coalesced fp32 reads -> LDS ->
// frag-ordered bf16 chunks with perfectly coalesced 16B stores.
// Kf chunk ci=(mt*2+kt)*64+lane : elem j = K[64t+16mt+n][32kt+8q+j]
// Vtf chunk ci=(kt2*4+d)*64+lane: elem j = V[64t+32kt2+8q+j][16d+n]
// ============================================================================
__global__ __launch_bounds__(256)
void prepass(const float* __restrict__ K, const float* __restrict__ V,
             const float* __restrict__ M, short* __restrict__ Kf,
             short* __restrict__ Vtf, float* __restrict__ Mf)
{
    __shared__ __align__(16) short K_lds[BK * KSTR];
    __shared__ __align__(16) short Vt_lds[DH * VSTR];

    const int tid = threadIdx.x;
    const int bh  = blockIdx.x >> 6;
    const int t   = blockIdx.x & 63;
    const size_t base = ((size_t)bh * S_LEN + (size_t)t * BK) * DH;

    // K tile -> LDS (coalesced float4 reads)
    #pragma unroll
    for (int it = 0; it < 4; ++it) {
        int idx = tid + 256 * it;
        int row = idx >> 4, c4 = idx & 15;
        float4 v = *(const float4*)(K + base + (size_t)row * DH + 4 * c4);
        short4v b4 = { f2bf(v.x), f2bf(v.y), f2bf(v.z), f2bf(v.w) };
        *(short4v*)&K_lds[row * KSTR + 4 * c4] = b4;
    }
    // V tile -> LDS transposed (coalesced float4 reads, 4x4 block per thread)
    {
        int kb = tid >> 4, db = tid & 15;
        const float* vp = V + base + (size_t)(4 * kb) * DH + 4 * db;
        float4 r0 = *(const float4*)(vp);
        float4 r1 = *(const float4*)(vp + DH);
        float4 r2 = *(const float4*)(vp + 2 * DH);
        float4 r3 = *(const float4*)(vp + 3 * DH);
        short4v c0 = { f2bf(r0.x), f2bf(r1.x), f2bf(r2.x), f2bf(r3.x) };
        short4v c1 = { f2bf(r0.y), f2bf(r1.y), f2bf(r2.y), f2bf(r3.y) };
        short4v c2 = { f2bf(r0.z), f2bf(r1.z), f2bf(r2.z), f2bf(r3.z) };
        short4v c3 = { f2bf(r0.w), f2bf(r1.w), f2bf(r2.w), f2bf(r3.w) };
        *(short4v*)&Vt_lds[(4 * db + 0) * VSTR + 4 * kb] = c0;
        *(short4v*)&Vt_lds[(4 * db + 1) * VSTR + 4 * kb] = c1;
        *(short4v*)&Vt_lds[(4 * db + 2) * VSTR + 4 * kb] = c2;
        *(short4v*)&Vt_lds[(4 * db + 3) * VSTR + 4 * kb] = c3;
    }
    __syncthreads();

    const size_t obase = (size_t)(bh * NTILE + t) * 4096;
    #pragma unroll
    for (int e = 0; e < 2; ++e) {
        int ci = tid + 256 * e;                 // 0..511
        int lane = ci & 63, n = lane & 15, q = lane >> 4;
        // K frag chunk: kt = (ci>>6)&1, mt = ci>>7
        {
            int kt = (ci >> 6) & 1, mt = ci >> 7;
            short8 f = *(const short8*)&K_lds[(16 * mt + n) * KSTR + 32 * kt + 8 * q];
            *(short8*)&Kf[obase + (size_t)ci * 8] = f;
        }
        // V^T frag chunk: d = (ci>>6)&3, kt2 = (ci>>8)&1
        {
            int d = (ci >> 6) & 3, kt2 = (ci >> 8) & 1;
            short8 g = *(const short8*)&Vt_lds[(16 * d + n) * VSTR + 32 * kt2 + 8 * q];
            *(short8*)&Vtf[obase + (size_t)ci * 8] = g;
        }
    }
    // mask: fold *log2e and the fixed shift; one bh per b_idx does it
    if ((bh % NHEADS) == 0 && tid < 16) {
        int b_idx = bh / NHEADS;
        float4 mv = *(const float4*)(M + (size_t)b_idx * S_LEN + t * BK + 4 * tid);
        mv.x = mv.x * LOG2E + MCONST;
        mv.y = mv.y * LOG2E + MCONST;
        mv.z = mv.z * LOG2E + MCONST;
        mv.w = mv.w * LOG2E + MCONST;
        *(float4*)&Mf[(size_t)b_idx * S_LEN + t * BK + 4 * tid] = mv;
    }
}

// ============================================================================
// Flash kernel v3: fixed-shift softmax (no max/rescale chain), l via ones-MFMA,
// 1-op bf16 pack via v_perm, barrier-free K-loop.
// ============================================================================
__global__ __launch_bounds__(256, 3)
void fa3(const float* __restrict__ Q, const short* __restrict__ Kf,
         const short* __restrict__ Vtf, const float* __restrict__ Mf,
         float* __restrict__ O)
{
    __shared__ __align__(16) short P_lds[BQ * PSTR];

    const int tid  = threadIdx.x;
    const int w    = tid >> 6;
    const int lane = tid & 63;
    const int n    = lane & 15;
    const int quad = lane >> 4;

    const int bid  = blockIdx.x;
    const int x    = bid & 7;
    const int g    = bid >> 3;
    const int bh   = x + 8 * (g >> 5);
    const int qblk = g & 31;
    const bool special = (qblk == QBLKS - 1);

    const size_t base  = (size_t)bh * S_LEN * DH;
    const int    b_idx = bh / NHEADS;

    // ---- Q fragments, scaled by 0.125*log2e (log2-domain scores)
    const float QSCALE = 0.125f * LOG2E;
    const int q0 = qblk * BQ + w * 32;
    short8 qf[2][2];
    #pragma unroll
    for (int s = 0; s < 2; ++s) {
        const float* qp = Q + base + (size_t)(q0 + 16 * s + n) * DH;
        #pragma unroll
        for (int kt = 0; kt < 2; ++kt) {
            const float* p = qp + 32 * kt + 8 * quad;
            float4 a = *(const float4*)p;
            float4 b = *(const float4*)(p + 4);
            short8 f;
            f[0] = f2bf(a.x * QSCALE); f[1] = f2bf(a.y * QSCALE);
            f[2] = f2bf(a.z * QSCALE); f[3] = f2bf(a.w * QSCALE);
            f[4] = f2bf(b.x * QSCALE); f[5] = f2bf(b.y * QSCALE);
            f[6] = f2bf(b.z * QSCALE); f[7] = f2bf(b.w * QSCALE);
            qf[s][kt] = f;
        }
    }

    f32x4 o[4][2];
    #pragma unroll
    for (int d = 0; d < 4; ++d)
        #pragma unroll
        for (int s = 0; s < 2; ++s) o[d][s] = (f32x4){0.f, 0.f, 0.f, 0.f};
    f32x4 lsum[2] = { (f32x4){0.f,0.f,0.f,0.f}, (f32x4){0.f,0.f,0.f,0.f} };

    const short8 ONES = { 0x3F80, 0x3F80, 0x3F80, 0x3F80,
                          0x3F80, 0x3F80, 0x3F80, 0x3F80 };  // bf16 1.0
    const float* mrow = Mf + (size_t)b_idx * S_LEN;

    for (int t = 0; t < NTILE; ++t) {
        if (special && t >= NTILE - 2) {
            // last 128x128 block: p = 2^-13 (bf16 0x3900) on/below diag, 0 above
            #pragma unroll
            for (int s = 0; s < 2; ++s) {
                int ql = w * 32 + 16 * s + n;
                int qrow = ql;
                #pragma unroll
                for (int mt = 0; mt < 4; ++mt) {
                    int k0 = (t - (NTILE - 2)) * BK + 16 * mt + 4 * quad;
                    unsigned d0 = (k0     > ql ? 0u : 0x3900u)
                                | (k0 + 1 > ql ? 0u : 0x39000000u);
                    unsigned d1 = (k0 + 2 > ql ? 0u : 0x3900u)
                                | (k0 + 3 > ql ? 0u : 0x39000000u);
                    *(uint2*)&P_lds[qrow * PSTR + 16 * mt + 4 * quad] = make_uint2(d0, d1);
                }
            }
        } else {
            // K fragments straight from global (pre-swizzled A-frag order)
            const short* kb = Kf + (size_t)(bh * NTILE + t) * 4096 + (size_t)lane * 8;
            short8 kfr[4][2];
            #pragma unroll
            for (int mt = 0; mt < 4; ++mt)
                #pragma unroll
                for (int kt = 0; kt < 2; ++kt)
                    kfr[mt][kt] = *(const short8*)(kb + (mt * 2 + kt) * 512);
            f32x4 mk[4];
            #pragma unroll
            for (int mt = 0; mt < 4; ++mt)
                mk[mt] = *(const f32x4*)(mrow + t * BK + 16 * mt + 4 * quad);

            f32x4 acc[4][2];
            #pragma unroll
            for (int mt = 0; mt < 4; ++mt)
                #pragma unroll
                for (int s = 0; s < 2; ++s) {
                    f32x4 c = (f32x4){0.f, 0.f, 0.f, 0.f};
                    c = __builtin_amdgcn_mfma_f32_16x16x32_bf16(kfr[mt][0], qf[s][0], c, 0, 0, 0);
                    c = __builtin_amdgcn_mfma_f32_16x16x32_bf16(kfr[mt][1], qf[s][1], c, 0, 0, 0);
                    acc[mt][s] = c;
                }

            // p = exp2(acc + mk'); pack 2 bf16 (truncate) per v_perm; store b64
            #pragma unroll
            for (int s = 0; s < 2; ++s) {
                int qrow = w * 32 + 16 * s + n;
                #pragma unroll
                for (int mt = 0; mt < 4; ++mt) {
                    float p0 = __builtin_amdgcn_exp2f(acc[mt][s][0] + mk[mt][0]);
                    float p1 = __builtin_amdgcn_exp2f(acc[mt][s][1] + mk[mt][1]);
                    float p2 = __builtin_amdgcn_exp2f(acc[mt][s][2] + mk[mt][2]);
                    float p3 = __builtin_amdgcn_exp2f(acc[mt][s][3] + mk[mt][3]);
                    unsigned d0 = __builtin_amdgcn_perm(
                        __builtin_bit_cast(unsigned, p1),
                        __builtin_bit_cast(unsigned, p0), 0x07060302u);
                    unsigned d1 = __builtin_amdgcn_perm(
                        __builtin_bit_cast(unsigned, p3),
                        __builtin_bit_cast(unsigned, p2), 0x07060302u);
                    *(uint2*)&P_lds[qrow * PSTR + 16 * mt + 4 * quad] = make_uint2(d0, d1);
                }
            }
        }

        // V^T fragments straight from global
        const short* vb = Vtf + (size_t)(bh * NTILE + t) * 4096 + (size_t)lane * 8;
        short8 vfr[2][4];
        #pragma unroll
        for (int kt2 = 0; kt2 < 2; ++kt2)
            #pragma unroll
            for (int d = 0; d < 4; ++d)
                vfr[kt2][d] = *(const short8*)(vb + (kt2 * 4 + d) * 512);

        // O^T += V^T * P^T ;  l += ones * P^T  (row-sum on the MFMA pipe)
        #pragma unroll
        for (int kt2 = 0; kt2 < 2; ++kt2) {
            short8 pf0 = *(const short8*)&P_lds[(w * 32 + n) * PSTR + 32 * kt2 + 8 * quad];
            short8 pf1 = *(const short8*)&P_lds[(w * 32 + 16 + n) * PSTR + 32 * kt2 + 8 * quad];
            lsum[0] = __builtin_amdgcn_mfma_f32_16x16x32_bf16(ONES, pf0, lsum[0], 0, 0, 0);
            lsum[1] = __builtin_amdgcn_mfma_f32_16x16x32_bf16(ONES, pf1, lsum[1], 0, 0, 0);
            #pragma unroll
            for (int d = 0; d < 4; ++d) {
                o[d][0] = __builtin_amdgcn_mfma_f32_16x16x32_bf16(vfr[kt2][d], pf0, o[d][0], 0, 0, 0);
                o[d][1] = __builtin_amdgcn_mfma_f32_16x16x32_bf16(vfr[kt2][d], pf1, o[d][1], 0, 0, 0);
            }
        }
    }

    // epilogue: every C row of lsum holds l(q) for q = col; use reg 0
    #pragma unroll
    for (int s = 0; s < 2; ++s) {
        float inv = 1.0f / lsum[s][0];
        int qg = q0 + 16 * s + n;
        float* op = O + base + (size_t)qg * DH;
        #pragma unroll
        for (int d = 0; d < 4; ++d) {
            f32x4 r = o[d][s] * inv;
            *(f32x4*)(op + 16 * d + 4 * quad) = r;
        }
    }
}

extern "C" void kernel_launch(void* const* d_in, const int* in_sizes, int n_in,
                              void* d_out, int out_size, void* d_ws, size_t ws_size,
                              hipStream_t stream) {
    const float* Q = (const float*)d_in[0];
    const float* K = (const float*)d_in[1];
    const float* V = (const float*)d_in[2];
    const float* M = (const float*)d_in[3];
    float* O = (float*)d_out;

    short* Kf  = (short*)d_ws;
    short* Vtf = Kf + (size_t)NKCH * 8;
    float* Mf  = (float*)(Vtf + (size_t)NKCH * 8);

    prepass<<<dim3(NBH * NTILE), dim3(256), 0, stream>>>(K, V, M, Kf, Vtf, Mf);
    fa3<<<dim3(NBH * QBLKS), dim3(256), 0, stream>>>(Q, Kf, Vtf, Mf, O);
}